// Round 10
// baseline (708.713 us; speedup 1.0000x reference)
//
#include <hip/hip_runtime.h>
#include <hip/hip_bf16.h>
#include <math.h>

// Problem constants (B=2,S=512 -> T=1024)
#define T_    1024
#define H_    2048
#define E_    64
#define I_    1024
#define TOPK  8
#define CAP   1024

// GEMM tiling
#define GTM   192        // token rows per tile
#define GBK   32         // K-chunk (rows of 32 bf16 = 64B in LDS)
#define GTN_G 64         // gateup out-cols per block
#define GTN_D 128        // down out-cols per block
#define NP    12800      // padded sorted-row capacity (<= 8192 + 64*63 + slack)

typedef __attribute__((ext_vector_type(8))) short  short8;
typedef __attribute__((ext_vector_type(8))) __bf16 bf16x8;
typedef __attribute__((ext_vector_type(4))) float  f32x4;

__device__ __forceinline__ unsigned short f2bf(float f) {
  unsigned int u = __float_as_uint(f);
  u += 0x7FFFu + ((u >> 16) & 1u);
  return (unsigned short)(u >> 16);
}

// pack two fp32 -> [bf16(lo) | bf16(hi)<<16] (round-half-up, 0.5ulp)
__device__ __forceinline__ unsigned int pack2bf(float lo, float hi) {
  const unsigned int a = __float_as_uint(hi) + 0x8000u;
  const unsigned int b = __float_as_uint(lo) + 0x8000u;
  return __builtin_amdgcn_perm(a, b, 0x07060302u);
}

__device__ __forceinline__ f32x4 mfma16(short8 a, short8 b, f32x4 c) {
  return __builtin_amdgcn_mfma_f32_16x16x32_bf16(
      __builtin_bit_cast(bf16x8, a), __builtin_bit_cast(bf16x8, b), c, 0, 0, 0);
}

__device__ __forceinline__ void gload16(const void* g, void* lds) {
  auto gp = reinterpret_cast<const __attribute__((address_space(1))) unsigned int*>(
      reinterpret_cast<uintptr_t>(g));
  auto lp = reinterpret_cast<__attribute__((address_space(3))) unsigned int*>(
      static_cast<unsigned int>(reinterpret_cast<uintptr_t>(lds)));
  __builtin_amdgcn_global_load_lds(gp, lp, 16, 0, 0);
}

// ---------------------------------------------------------------------------
// Kernel 1: router. One block per 4 tokens (grid 256).
// ---------------------------------------------------------------------------
__global__ __launch_bounds__(256) void router_k(
    const float* __restrict__ x, const float* __restrict__ rw,
    float* __restrict__ topw, int* __restrict__ counts, int* __restrict__ rows)
{
  __shared__ float xs[4][H_];
  __shared__ float lg[4][E_];
  const int t0  = blockIdx.x * 4;
  const int tid = threadIdx.x;
  for (int q = tid; q < 4 * (H_ / 4); q += 256) {
    const int tt = q >> 9;
    const int c  = q & 511;
    ((float4*)xs[tt])[c] = ((const float4*)(x + (size_t)(t0 + tt) * H_))[c];
  }
  __syncthreads();

  const int w = tid >> 6, lane = tid & 63;
  for (int ee = 0; ee < 16; ++ee) {
    const int e = w * 16 + ee;
    const float* wr = rw + (size_t)e * H_;
    float s0 = 0.f, s1 = 0.f, s2 = 0.f, s3 = 0.f;
    for (int h = lane; h < H_; h += 64) {
      const float wv = wr[h];
      s0 += wv * xs[0][h]; s1 += wv * xs[1][h];
      s2 += wv * xs[2][h]; s3 += wv * xs[3][h];
    }
    for (int off = 32; off; off >>= 1) {
      s0 += __shfl_xor(s0, off); s1 += __shfl_xor(s1, off);
      s2 += __shfl_xor(s2, off); s3 += __shfl_xor(s3, off);
    }
    if (lane == 0) { lg[0][e] = s0; lg[1][e] = s1; lg[2][e] = s2; lg[3][e] = s3; }
  }
  __syncthreads();

  {
    const int t = t0 + w;
    const float logit = lg[w][lane];
    float mx = logit;
    for (int off = 32; off; off >>= 1) mx = fmaxf(mx, __shfl_xor(mx, off));
    const float ex = expf(logit - mx);
    float sum = ex;
    for (int off = 32; off; off >>= 1) sum += __shfl_xor(sum, off);
    float p = ex / sum;
    for (int k = 0; k < TOPK; ++k) {
      float m = p; int mi = lane;
      for (int off = 32; off; off >>= 1) {
        const float om = __shfl_xor(m, off);
        const int   oi = __shfl_xor(mi, off);
        if (om > m || (om == m && oi < mi)) { m = om; mi = oi; }
      }
      if (lane == 0) {
        const int r = t * TOPK + k;
        topw[r] = m;
        const int pos = atomicAdd(&counts[mi], 1);
        rows[mi * CAP + pos] = r;
      }
      if (lane == mi) p = -1.f;
    }
  }
}

// ---------------------------------------------------------------------------
// Kernel 1b: exclusive scan of counts, 64-aligned bases.
// ---------------------------------------------------------------------------
__global__ void scan_k(const int* __restrict__ counts, int* __restrict__ base)
{
  if (threadIdx.x == 0) {
    int acc = 0;
    for (int e = 0; e < E_; ++e) { base[e] = acc; acc += (counts[e] + 63) & ~63; }
    base[E_] = acc;
  }
}

// ---------------------------------------------------------------------------
// Kernel 1c: gather x rows into expert-sorted bf16 xb; perm + cw arrays.
// ---------------------------------------------------------------------------
__global__ __launch_bounds__(256) void gather_k(
    const float* __restrict__ x, const int* __restrict__ rows,
    const int* __restrict__ counts, const int* __restrict__ base,
    const float* __restrict__ topw, unsigned short* __restrict__ xb,
    int* __restrict__ perm, float* __restrict__ cw_s)
{
  const int e   = blockIdx.x;
  const int cnt = counts[e];
  const int b0  = base[e];
  const int q   = threadIdx.x;
  for (int i = blockIdx.y; i < cnt; i += gridDim.y) {
    const int r = rows[e * CAP + i];
    const int t = r >> 3;
    const int p = b0 + i;
    const float* src = x + (size_t)t * H_ + q * 8;
    const float4 v0 = *(const float4*)src;
    const float4 v1 = *(const float4*)(src + 4);
    uint4 w;
    w.x = pack2bf(v0.x, v0.y); w.y = pack2bf(v0.z, v0.w);
    w.z = pack2bf(v1.x, v1.y); w.w = pack2bf(v1.z, v1.w);
    *(uint4*)(xb + (size_t)p * H_ + q * 8) = w;
    if (q == 0) { perm[p] = r; cw_s[p] = topw[r]; }
  }
}

// ---------------------------------------------------------------------------
// Kernel 2: gate/up GEMM. grid=(E, I/64), 512 threads (8 waves: 4m x 2n).
// AIRTIGHT SYNC (bisect round): per iter
//   __syncthreads -> gload A(i) + ds_write B(i) -> __syncthreads (drains all)
//   -> load B(i+1)->regs (overlaps compute; compiler-tracked) -> compute(i).
// Single-buffered LDS (20KB) -> up to 4 blocks/CU TLP hides exposed latency.
// A = xb contiguous bf16 (swizzled source chunks); B = reg-staged bf16.
// ---------------------------------------------------------------------------
__global__ __launch_bounds__(512, 4) void gateup_k(
    const unsigned short* __restrict__ xb, const float* __restrict__ wg,
    const float* __restrict__ wu, const float* __restrict__ cw_s,
    const int* __restrict__ counts, const int* __restrict__ base,
    unsigned short* __restrict__ hmid)
{
  const int e  = blockIdx.x;
  const int n0 = blockIdx.y * GTN_G;
  const int cnt = counts[e];
  if (cnt == 0) return;
  const int pbase = base[e];

  __shared__ __align__(16) unsigned short As[GTM][GBK];       // 12KB
  __shared__ __align__(16) unsigned short Bs[2][GTN_G][GBK];  // 8KB ([mat][row][k])

  const int tid = threadIdx.x;
  const int wid = tid >> 6, lane = tid & 63;
  const int wm = wid >> 1, wn = wid & 1;     // 4m x 2n: 48 rows x 32 cols/wave

  // A staging: round0 rows 0..127 (512 thr), round1 rows 128..191 (tid<256).
  const int arow0 = tid >> 2;
  const int arow1 = 128 + ((tid & 255) >> 2);
  const int ac0 = (((tid & 3) ^ ((arow0 >> 1) & 3))) * 8;   // ushort units
  const int ac1 = (((tid & 3) ^ ((arow1 >> 1) & 3))) * 8;
  const int ldsLane  = tid * 16;
  const int ldsLane1 = 8192 + (tid & 255) * 16;

  // B staging: mat = tid>>8; 256 thr/mat; 8 fp32 each; swizzled dest slot.
  const int bmat = tid >> 8, bq = tid & 255;
  const int bRow = bq >> 2, bS = bq & 3;
  const float* pbBase = (bmat ? wu : wg) + (size_t)e * I_ * H_
                      + (size_t)(n0 + bRow) * H_ + bS * 8;
  const int bp = bS ^ ((bRow >> 1) & 3);
  unsigned short* bdst = &Bs[bmat][bRow][bp * 8];

  int aoff[3], boff[2];
  const int h = lane >> 4;
#pragma unroll
  for (int mi = 0; mi < 3; ++mi) {
    const int r = wm * 48 + mi * 16 + (lane & 15);
    aoff[mi] = r * GBK + ((h ^ ((r >> 1) & 3)) * 8);
  }
#pragma unroll
  for (int ni = 0; ni < 2; ++ni) {
    const int r = wn * 32 + ni * 16 + (lane & 15);
    boff[ni] = r * GBK + ((h ^ ((r >> 1) & 3)) * 8);
  }

  const int nIter = H_ / GBK;   // 64

  for (int m0 = 0; m0 < cnt; m0 += GTM) {
    const unsigned short* pa0 = xb + (size_t)(pbase + m0 + arow0) * H_ + ac0;
    const unsigned short* pa1 = xb + (size_t)(pbase + m0 + arow1) * H_ + ac1;
    const float* pb = pbBase;

    f32x4 accg[3][2], accu[3][2];
#pragma unroll
    for (int i = 0; i < 3; ++i)
#pragma unroll
      for (int j = 0; j < 2; ++j)
#pragma unroll
        for (int q = 0; q < 4; ++q) { accg[i][j][q] = 0.f; accu[i][j][q] = 0.f; }

    // B(0) -> regs
    float4 b0 = *(const float4*)pb;
    float4 b1 = *(const float4*)(pb + 4);
    pb += GBK;

    for (int i = 0; i < nIter; ++i) {
      __syncthreads();      // prev compute done; LDS free to overwrite
      gload16(pa0, (char*)As + ldsLane);  pa0 += GBK;
      if (tid < 256) { gload16(pa1, (char*)As + ldsLane1); pa1 += GBK; }
      {                     // ds_write B(i)
        uint4 w;
        w.x = pack2bf(b0.x, b0.y); w.y = pack2bf(b0.z, b0.w);
        w.z = pack2bf(b1.x, b1.y); w.w = pack2bf(b1.z, b1.w);
        *(uint4*)bdst = w;
      }
      __syncthreads();      // vmcnt(0)+lgkmcnt(0) drain -> tile fully visible
      if (i + 1 < nIter) {  // B(i+1) -> regs, overlaps compute
        b0 = *(const float4*)pb;
        b1 = *(const float4*)(pb + 4);
        pb += GBK;
      }
      // compute tile i
      {
        const unsigned short* A  = &As[0][0];
        const unsigned short* Bg = &Bs[0][0][0];
        const unsigned short* Bu = &Bs[1][0][0];
        short8 af[3];
#pragma unroll
        for (int mi = 0; mi < 3; ++mi) af[mi] = *(const short8*)&A[aoff[mi]];
#pragma unroll
        for (int ni = 0; ni < 2; ++ni) {
          const short8 bg = *(const short8*)&Bg[boff[ni]];
          const short8 bu = *(const short8*)&Bu[boff[ni]];
#pragma unroll
          for (int mi = 0; mi < 3; ++mi) {
            accg[mi][ni] = mfma16(af[mi], bg, accg[mi][ni]);
            accu[mi][ni] = mfma16(af[mi], bu, accu[mi][ni]);
          }
        }
      }
    }
    // epilogue: h = silu(g)*u*cw -> hmid (sorted rows, bf16)
#pragma unroll
    for (int mi = 0; mi < 3; ++mi)
#pragma unroll
      for (int ni = 0; ni < 2; ++ni)
#pragma unroll
        for (int j = 0; j < 4; ++j) {
          const int ml = wm * 48 + mi * 16 + (lane >> 4) * 4 + j;
          if (m0 + ml < cnt) {
            const int p = pbase + m0 + ml;
            const float cw = cw_s[p];
            const float g = accg[mi][ni][j], uu = accu[mi][ni][j];
            const float hv = g / (1.f + __expf(-g)) * uu * cw;
            hmid[(size_t)p * I_ + n0 + wn * 32 + ni * 16 + (lane & 15)] = f2bf(hv);
          }
        }
  }
}

// ---------------------------------------------------------------------------
// Kernel 3: down GEMM. grid=(E, H/128), 512 threads. Same airtight structure.
// A = hmid sorted bf16 via DMA; B = wd reg-staged bf16.
// ---------------------------------------------------------------------------
__global__ __launch_bounds__(512, 4) void down_k(
    const unsigned short* __restrict__ hmid, const float* __restrict__ wd,
    const int* __restrict__ counts, const int* __restrict__ base,
    const int* __restrict__ perm, float* __restrict__ outp, const int atomicMode)
{
  const int e  = blockIdx.x;
  const int n0 = blockIdx.y * GTN_D;
  const int cnt = counts[e];
  if (cnt == 0) return;
  const int pbase = base[e];

  __shared__ __align__(16) unsigned short As[GTM][GBK];       // 12KB
  __shared__ __align__(16) unsigned short Bs[GTN_D][GBK];     // 8KB

  const int tid = threadIdx.x;
  const int wid = tid >> 6, lane = tid & 63;
  const int wm = wid >> 1, wn = wid & 1;     // 4m x 2n: 48 rows x 64 cols/wave

  const int arow0 = tid >> 2;
  const int arow1 = 128 + ((tid & 255) >> 2);
  const int ac0 = (((tid & 3) ^ ((arow0 >> 1) & 3))) * 8;
  const int ac1 = (((tid & 3) ^ ((arow1 >> 1) & 3))) * 8;
  const int ldsLane  = tid * 16;
  const int ldsLane1 = 8192 + (tid & 255) * 16;

  const int bRow = tid >> 2, bS = tid & 3;   // 128 rows x 4 chunks
  const float* pbBase = wd + (size_t)e * H_ * I_
                      + (size_t)(n0 + bRow) * I_ + bS * 8;
  const int bp = bS ^ ((bRow >> 1) & 3);
  unsigned short* bdst = &Bs[bRow][bp * 8];

  int aoff[3], boff[4];
  const int h = lane >> 4;
#pragma unroll
  for (int mi = 0; mi < 3; ++mi) {
    const int r = wm * 48 + mi * 16 + (lane & 15);
    aoff[mi] = r * GBK + ((h ^ ((r >> 1) & 3)) * 8);
  }
#pragma unroll
  for (int ni = 0; ni < 4; ++ni) {
    const int r = wn * 64 + ni * 16 + (lane & 15);
    boff[ni] = r * GBK + ((h ^ ((r >> 1) & 3)) * 8);
  }

  const int nIter = I_ / GBK;   // 32

  for (int m0 = 0; m0 < cnt; m0 += GTM) {
    const unsigned short* pa0 = hmid + (size_t)(pbase + m0 + arow0) * I_ + ac0;
    const unsigned short* pa1 = hmid + (size_t)(pbase + m0 + arow1) * I_ + ac1;
    const float* pb = pbBase;

    f32x4 acc[3][4];
#pragma unroll
    for (int i = 0; i < 3; ++i)
#pragma unroll
      for (int j = 0; j < 4; ++j)
#pragma unroll
        for (int q = 0; q < 4; ++q) acc[i][j][q] = 0.f;

    float4 b0 = *(const float4*)pb;
    float4 b1 = *(const float4*)(pb + 4);
    pb += GBK;

    for (int i = 0; i < nIter; ++i) {
      __syncthreads();
      gload16(pa0, (char*)As + ldsLane);  pa0 += GBK;
      if (tid < 256) { gload16(pa1, (char*)As + ldsLane1); pa1 += GBK; }
      {
        uint4 w;
        w.x = pack2bf(b0.x, b0.y); w.y = pack2bf(b0.z, b0.w);
        w.z = pack2bf(b1.x, b1.y); w.w = pack2bf(b1.z, b1.w);
        *(uint4*)bdst = w;
      }
      __syncthreads();
      if (i + 1 < nIter) {
        b0 = *(const float4*)pb;
        b1 = *(const float4*)(pb + 4);
        pb += GBK;
      }
      {
        const unsigned short* A = &As[0][0];
        const unsigned short* B = &Bs[0][0];
        short8 af[3];
#pragma unroll
        for (int mi = 0; mi < 3; ++mi) af[mi] = *(const short8*)&A[aoff[mi]];
#pragma unroll
        for (int ni = 0; ni < 4; ++ni) {
          const short8 bw = *(const short8*)&B[boff[ni]];
#pragma unroll
          for (int mi = 0; mi < 3; ++mi)
            acc[mi][ni] = mfma16(af[mi], bw, acc[mi][ni]);
        }
      }
    }
#pragma unroll
    for (int mi = 0; mi < 3; ++mi)
#pragma unroll
      for (int ni = 0; ni < 4; ++ni)
#pragma unroll
        for (int j = 0; j < 4; ++j) {
          const int ml = wm * 48 + mi * 16 + (lane >> 4) * 4 + j;
          if (m0 + ml < cnt) {
            const int p = pbase + m0 + ml;
            const int r = perm[p];
            const int col = n0 + wn * 64 + ni * 16 + (lane & 15);
            if (atomicMode) atomicAdd(&outp[(size_t)(r >> 3) * H_ + col], acc[mi][ni][j]);
            else            outp[(size_t)r * H_ + col] = acc[mi][ni][j];
          }
        }
  }
}

// ---------------------------------------------------------------------------
// Kernel 4: combine partials over k=0..7 (deterministic fixed-order sum)
// ---------------------------------------------------------------------------
__global__ __launch_bounds__(256) void combine_k(
    const float* __restrict__ partial, float* __restrict__ out)
{
  const int idx = blockIdx.x * 256 + threadIdx.x;
  const int t = idx >> 9;
  const int c = idx & 511;
  float4 s; s.x = 0.f; s.y = 0.f; s.z = 0.f; s.w = 0.f;
#pragma unroll
  for (int k = 0; k < TOPK; ++k) {
    const float4 v = *(const float4*)(partial + (size_t)(t * TOPK + k) * H_ + c * 4);
    s.x += v.x; s.y += v.y; s.z += v.z; s.w += v.w;
  }
  *(float4*)(out + (size_t)t * H_ + c * 4) = s;
}

// ---------------------------------------------------------------------------
extern "C" void kernel_launch(void* const* d_in, const int* in_sizes, int n_in,
                              void* d_out, int out_size, void* d_ws, size_t ws_size,
                              hipStream_t stream)
{
  const float* x  = (const float*)d_in[0];
  const float* rw = (const float*)d_in[1];
  const float* wg = (const float*)d_in[2];
  const float* wu = (const float*)d_in[3];
  const float* wd = (const float*)d_in[4];
  float* out = (float*)d_out;

  char* ws = (char*)d_ws;
  const size_t OFF_TOPW = 1024;                                  // counts @0
  const size_t OFF_ROWS = OFF_TOPW + (size_t)T_ * TOPK * 4;
  const size_t OFF_BASE = OFF_ROWS + (size_t)E_ * CAP * 4;
  const size_t OFF_PERM = OFF_BASE + 1024;
  const size_t OFF_CW   = OFF_PERM + (size_t)NP * 4;
  const size_t OFF_XB   = (OFF_CW + (size_t)NP * 4 + 1023) & ~(size_t)1023;
  const size_t OFF_HMID = OFF_XB + (size_t)NP * H_ * 2;
  const size_t OFF_PART = OFF_HMID + (size_t)NP * I_ * 2;
  const size_t TOTAL    = OFF_PART + (size_t)T_ * TOPK * H_ * 4;

  int*   counts = (int*)ws;
  float* topw   = (float*)(ws + OFF_TOPW);
  int*   rows   = (int*)(ws + OFF_ROWS);
  int*   basep  = (int*)(ws + OFF_BASE);
  int*   perm   = (int*)(ws + OFF_PERM);
  float* cw_s   = (float*)(ws + OFF_CW);
  unsigned short* xb   = (unsigned short*)(ws + OFF_XB);
  unsigned short* hmid = (unsigned short*)(ws + OFF_HMID);
  float* partial = (float*)(ws + OFF_PART);

  const int usePartial = (ws_size >= TOTAL) ? 1 : 0;

  hipMemsetAsync(counts, 0, E_ * sizeof(int), stream);
  router_k<<<T_ / 4, 256, 0, stream>>>(x, rw, topw, counts, rows);
  scan_k<<<1, 64, 0, stream>>>(counts, basep);
  gather_k<<<dim3(E_, 256), 256, 0, stream>>>(x, rows, counts, basep, topw, xb, perm, cw_s);
  gateup_k<<<dim3(E_, I_ / GTN_G), 512, 0, stream>>>(xb, wg, wu, cw_s, counts, basep, hmid);
  if (usePartial) {
    down_k<<<dim3(E_, H_ / GTN_D), 512, 0, stream>>>(hmid, wd, counts, basep, perm, partial, 0);
    combine_k<<<(T_ * H_ / 4) / 256, 256, 0, stream>>>(partial, out);
  } else {
    hipMemsetAsync(out, 0, (size_t)out_size * sizeof(float), stream);
    down_k<<<dim3(E_, H_ / GTN_D), 512, 0, stream>>>(hmid, wd, counts, basep, perm, out, 1);
  }
}